// Round 5
// baseline (1030.236 us; speedup 1.0000x reference)
//
#include <hip/hip_runtime.h>
#include <math.h>

#define TAU_MAX  524287     // chunk sig[16t .. 16t+15] valid iff 0 <= t <= TAU_MAX
#define T_OUT    524287
#define RING     1152       // ring capacity in chunks
#define R        4          // outputs per thread
#define NTHR     256
#define TB       (NTHR*R)   // 1024 outputs per block

// ---- LDS layout: chunk = 16 complex = 4 units of 16B (unit = 4 bf16 (re,im) pairs).
// Unit U lives at BYTE offset 16*U + 8*(U>>3): 8 units (128B) per row + 8B pad.
// Reads: lane slot-stride 4 -> byte stride 272 (68 words, ==4 mod 32 banks) ->
// 8 consecutive lanes cover all 32 banks exactly once. Writes: U stride 1 ->
// also exactly 1 dword/bank per 8 lanes. Conflict-free both directions.
// Total: 4608 units -> 78336 B (76.5 KiB) -> 2 blocks/CU.
__device__ __forceinline__ int unit_word(int U) {      // word index
    return (U << 2) + ((U >> 3) << 1);
}
// Slot base word: units 4sl..4sl+3 are contiguous (words +0,+4,+8,+12).
__device__ __forceinline__ int slot_word(int sl) {
    return (sl << 4) + ((sl >> 1) << 1);
}

__device__ __forceinline__ int slot_of(int tau) {
    return (int)(((unsigned)(tau + 4 * RING)) % (unsigned)RING);
}

// round-to-nearest-even f32 -> bf16
__device__ __forceinline__ unsigned f2bf(float f) {
    unsigned u = __float_as_uint(f);
    u += 0x7fffu + ((u >> 16) & 1u);
    return u >> 16;
}
__device__ __forceinline__ unsigned pack2(float re, float im) {
    return f2bf(re) | (f2bf(im) << 16);
}

// Load+pack unit q of chunk tau: elements 4q..4q+3 as (re,im) bf16 pairs.
__device__ __forceinline__ uint4 load_pack_unit(const float* __restrict__ sre,
                                                const float* __restrict__ sim,
                                                int tau, int q)
{
    uint4 u = make_uint4(0u, 0u, 0u, 0u);
    if ((unsigned)tau <= (unsigned)TAU_MAX) {
        const float4 a = *reinterpret_cast<const float4*>(sre + 16 * tau + 4 * q);
        const float4 b = *reinterpret_cast<const float4*>(sim + 16 * tau + 4 * q);
        u.x = pack2(a.x, b.x); u.y = pack2(a.y, b.y);
        u.z = pack2(a.z, b.z); u.w = pack2(a.w, b.w);
    }
    return u;
}

// One chunk position: thread chunk tau = t0+515-d at ring slot sl.
// Element j feeds branch (16-j)&15 of output t0+r; coeff row = d-4+r for j>=1,
// row+1 for j==0 (coeff[16*row+16] == coeff[16*(row+1)+0]).
// GK: 0 = no guard, 1 = low guard (head), 2 = high guard (tail).
template<int GK>
__device__ __forceinline__ void step(int d, int sl,
                                     const float* __restrict__ coeff,
                                     const unsigned* __restrict__ lds,
                                     float (&are)[16][R], float (&aim)[16][R])
{
    float cre[16], cim[16];
    const int bw = slot_word(sl);
    #pragma unroll
    for (int q = 0; q < 4; ++q) {
        const uint4 u = *reinterpret_cast<const uint4*>(&lds[bw + 4 * q]);
        const unsigned w[4] = {u.x, u.y, u.z, u.w};
        #pragma unroll
        for (int m = 0; m < 4; ++m) {
            cre[4 * q + m] = __uint_as_float(w[m] << 16);
            cim[4 * q + m] = __uint_as_float(w[m] & 0xffff0000u);
        }
    }
    #pragma unroll
    for (int r = 0; r < R; ++r) {
        const int row = d - 4 + r;
        if (GK == 0 || (GK == 1 ? (row >= 0) : (row <= 1023))) {
            #pragma unroll
            for (int i = 1; i < 16; ++i) {
                const float cf = coeff[16 * row + i];   // uniform -> s_load
                are[i][r] = fmaf(cf, cre[16 - i], are[i][r]);
                aim[i][r] = fmaf(cf, cim[16 - i], aim[i][r]);
            }
        }
        if (GK == 0 || (GK == 1 ? (row >= -1) : (row <= 1022))) {
            const float cf = coeff[16 * row + 16];
            are[0][r] = fmaf(cf, cre[0], are[0][r]);
            aim[0][r] = fmaf(cf, cim[0], aim[0][r]);
        }
    }
}

__device__ __forceinline__ void dec_slot(int& sl) {
    if (--sl < 0) sl += RING;
}

__global__ __launch_bounds__(NTHR, 2)
void wdm_kernel(const float* __restrict__ sre,
                const float* __restrict__ sim,
                const float* __restrict__ coeff,
                float* __restrict__ out)
{
    extern __shared__ unsigned lds[];
    const int tid = threadIdx.x;
    const int T0  = blockIdx.x * TB;
    const int t0  = T0 + tid * R;

    // ---- prologue: stage chunks [T0+452, T0+1539] (1088 chunks = 4352 units, 17/thread)
    #pragma unroll 1
    for (int j = 0; j < 17; ++j) {
        const int u = tid + NTHR * j;
        const int tau = T0 + 452 + (u >> 2);
        const int q = u & 3;
        const uint4 v = load_pack_unit(sre, sim, tau, q);
        *reinterpret_cast<uint4*>(&lds[unit_word(4 * slot_of(tau) + q)]) = v;
    }
    __syncthreads();

    float are[16][R], aim[16][R];
    #pragma unroll
    for (int i = 0; i < 16; ++i)
        #pragma unroll
        for (int r = 0; r < R; ++r) { are[i][r] = 0.f; aim[i][r] = 0.f; }

    int sl = slot_of(t0 + 515);

    // head: d in [0,4), low-guarded
    #pragma unroll 1
    for (int d = 0; d < 4; ++d) { step<1>(d, sl, coeff, lds, are, aim); dec_slot(sl); }

    // tile 0: d in [4,64); prefetch window-1 chunks [T0+388, T0+451]
    {
        const int stau = T0 + 388 + (tid >> 2);
        const int sq   = tid & 3;
        const uint4 sv = load_pack_unit(sre, sim, stau, sq);
        #pragma unroll 4
        for (int d = 4; d < 64; ++d) { step<0>(d, sl, coeff, lds, are, aim); dec_slot(sl); }
        *reinterpret_cast<uint4*>(&lds[unit_word(4 * slot_of(stau) + sq)]) = sv;
        __syncthreads();
    }

    // tiles 1..14: prefetch window-(k+1) chunks [T0+388-64k, T0+451-64k]
    #pragma unroll 1
    for (int k = 1; k <= 14; ++k) {
        const int stau = T0 + 388 - 64 * k + (tid >> 2);
        const int sq   = tid & 3;
        const uint4 sv = load_pack_unit(sre, sim, stau, sq);
        const int d0 = 64 * k;
        #pragma unroll 4
        for (int d = d0; d < d0 + 64; ++d) { step<0>(d, sl, coeff, lds, are, aim); dec_slot(sl); }
        *reinterpret_cast<uint4*>(&lds[unit_word(4 * slot_of(stau) + sq)]) = sv;
        __syncthreads();
    }

    // tile 15: prefetch the 4 tail chunks [T0-512, T0-509] (16 units, tid<16)
    {
        uint4 sv = make_uint4(0u, 0u, 0u, 0u);
        int swd = 0;
        const bool st = (tid < 16);
        if (st) {
            const int stau = T0 - 512 + (tid >> 2);
            sv  = load_pack_unit(sre, sim, stau, tid & 3);
            swd = unit_word(4 * slot_of(stau) + (tid & 3));
        }
        #pragma unroll 4
        for (int d = 960; d < 1024; ++d) { step<0>(d, sl, coeff, lds, are, aim); dec_slot(sl); }
        if (st) *reinterpret_cast<uint4*>(&lds[swd]) = sv;
        __syncthreads();
    }

    // tail: d in [1024,1028), high-guarded
    #pragma unroll 1
    for (int d = 1024; d < 1028; ++d) { step<2>(d, sl, coeff, lds, are, aim); dec_slot(sl); }

    // ---- epilogue: 16-point inverse DFT across branches, REAL part only
    #pragma unroll 1
    for (int ch = 0; ch < 16; ++ch) {
        const float ang = 0.39269908169872414f * (float)ch;  // 2*pi*ch/16
        const float wc = cosf(ang), ws = sinf(ang);
        float wr = 1.f, wi = 0.f;
        float o[R];
        #pragma unroll
        for (int r = 0; r < R; ++r) o[r] = 0.f;
        #pragma unroll
        for (int i = 0; i < 16; ++i) {
            #pragma unroll
            for (int r = 0; r < R; ++r)
                o[r] = fmaf(wr, are[i][r], fmaf(-wi, aim[i][r], o[r]));
            const float nwr = wr * wc - wi * ws;
            const float nwi = wr * ws + wi * wc;
            wr = nwr; wi = nwi;
        }
        float* orow = out + (long)ch * T_OUT;
        #pragma unroll
        for (int r = 0; r < R; ++r) {
            const int t = t0 + r;
            if (t < T_OUT) orow[t] = o[r];
        }
    }
}

extern "C" void kernel_launch(void* const* d_in, const int* in_sizes, int n_in,
                              void* d_out, int out_size, void* d_ws, size_t ws_size,
                              hipStream_t stream)
{
    const float* sre   = (const float*)d_in[0];
    const float* sim   = (const float*)d_in[1];
    const float* coeff = (const float*)d_in[2];
    float* out = (float*)d_out;

    // 512 blocks x 1024 outputs = 524288 >= 524287.
    // LDS: unit_word(4608)*4 = 78336 B -> 2 blocks/CU.
    const int lds_bytes = ((4608 << 2) + ((4608 >> 3) << 1)) * 4;
    wdm_kernel<<<dim3(512), dim3(NTHR), lds_bytes, stream>>>(sre, sim, coeff, out);
}